// Round 4
// baseline (2727.274 us; speedup 1.0000x reference)
//
#include <hip/hip_runtime.h>
#include <stdint.h>

typedef _Float16 half8 __attribute__((ext_vector_type(8)));
typedef float floatx16 __attribute__((ext_vector_type(16)));

#define ALPHA_ 1.0f
#define BETA_ 0.25f
#define NUM_EMBEDS 8192
#define EMBED_DIM 512
#define B_ 32
#define T_ 256
#define N_TOK 8192
#define TOKB 64
#define KCH 1024
#define MARGIN 0.25f
#define CAP 2000000

// ---------------- ws layout (bytes) ----------------
// wexact  @ 0        (64 KB)  u64 packed exact min: key<<32 | code
// cnormP  @ 65536    (32 KB)  ||c||^2 + 4096  (bias => scores positive)
// counts  @ 98304    (32 KB)
// sse     @ 131072   (4 B)
// counter @ 131076   (4 B)    candidate count
// cb_h    @ 1  MB    (8 MB)   f16 codebook [k][d]
// zt_h    @ 9  MB    (8 MB)   f16 -2*z transposed [n][d]
// list    @ 17 MB    (8 MB)   u32 candidates (tok<<13 | code)
// ---------------------------------------------------

typedef __attribute__((address_space(1))) const void ga_void;
typedef __attribute__((address_space(3))) void ls_void;
__device__ __forceinline__ void gl_lds16(const void* g, void* l) {
    __builtin_amdgcn_global_load_lds((ga_void*)g, (ls_void*)l, 16, 0, 0);
}

__global__ void pack_cb_kernel(const float* __restrict__ cb, _Float16* __restrict__ h,
                               float* __restrict__ cnormP) {
    int row = blockIdx.x * 4 + (threadIdx.x >> 6);
    int lane = threadIdx.x & 63;
    const float* src = cb + (size_t)row * EMBED_DIM + lane * 8;
    float4 v0 = *(const float4*)src;
    float4 v1 = *(const float4*)(src + 4);
    float x[8] = {v0.x, v0.y, v0.z, v0.w, v1.x, v1.y, v1.z, v1.w};
    half8 hh;
    float s = 0.f;
#pragma unroll
    for (int j = 0; j < 8; ++j) { s += x[j] * x[j]; hh[j] = (_Float16)x[j]; }
    *(half8*)(h + (size_t)row * EMBED_DIM + lane * 8) = hh;
#pragma unroll
    for (int d = 32; d; d >>= 1) s += __shfl_xor(s, d, 64);
    if (lane == 0) cnormP[row] = s + 4096.0f;
}

// transpose z (b,d,t) -> (n, d), pack f16(-2z)
__global__ void pack_z_kernel(const float* __restrict__ z, _Float16* __restrict__ h) {
    int tid = threadIdx.x;
    int lane = tid & 63, ds = tid >> 6;
    int b = blockIdx.x >> 2;
    int t = ((blockIdx.x & 3) << 6) + lane;
    size_t n = (size_t)b * T_ + t;
    for (int g = 0; g < 16; ++g) {
        int d0 = g * 32 + ds * 8;
        const float* src = z + ((size_t)b * EMBED_DIM + d0) * T_ + t;
        half8 hh;
#pragma unroll
        for (int j = 0; j < 8; ++j) hh[j] = (_Float16)(-2.0f * src[(size_t)j * T_]);
        *(half8*)(h + n * EMBED_DIM + d0) = hh;
    }
}

// ---- pass 1: h-only argmin GEMM, 128 codes x 64 tokens, BK=64, swizzled LDS ----
__global__ __launch_bounds__(256, 4) void argmin_kernel(
    const _Float16* __restrict__ cb_h, const _Float16* __restrict__ zt_h,
    const float* __restrict__ cnormP, uint32_t* __restrict__ list,
    uint32_t* __restrict__ counter) {
    __shared__ _Float16 As[128 * 64];  // codes x 64k, row 128B, seg-swizzled
    __shared__ _Float16 Bs[64 * 64];   // tokens x 64k
    __shared__ uint32_t Rmin[TOKB];
    const int tid = threadIdx.x;
    const int l = tid & 63;
    const int wv = tid >> 6;
    const int l31 = l & 31;
    const int hf = l >> 5;
    const int wp = wv >> 1, wq = wv & 1;
    const int n0 = blockIdx.x * TOKB;
    const int kbase = blockIdx.y * KCH;

    if (tid < TOKB) Rmin[tid] = 0xFFFFFFFFu;

    // staging: 24 gl_lds of 1KB per superstep (A 16, B 8); 6 per wave; 8 rows/instr
    size_t st_off[6];
    _Float16* st_ldsb[6];
    bool st_isA[6];
#pragma unroll
    for (int j = 0; j < 6; ++j) {
        int id = wv * 6 + j;
        if (id < 16) {
            int row = id * 8 + (l >> 3);
            int seg = (l & 7) ^ (row & 7);
            st_off[j] = (size_t)row * EMBED_DIM + seg * 8;
            st_ldsb[j] = As + id * 512;
            st_isA[j] = true;
        } else {
            int row = (id - 16) * 8 + (l >> 3);
            int seg = (l & 7) ^ (row & 7);
            st_off[j] = (size_t)(n0 + row) * EMBED_DIM + seg * 8;
            st_ldsb[j] = Bs + (id - 16) * 512;
            st_isA[j] = false;
        }
    }
    auto stage = [&](int col, int ss) {
        size_t aoff = (size_t)(kbase + (col << 7)) * EMBED_DIM + (ss << 6);
        size_t boff = (size_t)(ss << 6);
#pragma unroll
        for (int j = 0; j < 6; ++j) {
            const _Float16* g = st_isA[j] ? (cb_h + st_off[j] + aoff) : (zt_h + st_off[j] + boff);
            gl_lds16(g, st_ldsb[j]);
        }
    };

    // fragment addressing (seg swizzle: phys = (ms*2+hf) ^ (row&7); row&7 == l31&7 for all)
    const int msk = l31 & 7;
    const _Float16* pA0 = As + (wp * 64 + l31) * 64;
    const _Float16* pA1 = pA0 + 32 * 64;
    const _Float16* pB = Bs + (wq * 32 + l31) * 64;

    stage(0, 0);
    for (int col = 0; col < 8; ++col) {
        floatx16 acc0, acc1;
#pragma unroll
        for (int r = 0; r < 16; ++r) { acc0[r] = 0.f; acc1[r] = 0.f; }

        for (int ss = 0; ss < 8; ++ss) {
            __syncthreads();  // staged data present (drains gl_lds)
            half8 fA0[4], fA1[4], fB[4];
#pragma unroll
            for (int ms = 0; ms < 4; ++ms) {
                int sg = (((ms << 1) | hf) ^ msk) << 3;
                fA0[ms] = *(const half8*)(pA0 + sg);
                fA1[ms] = *(const half8*)(pA1 + sg);
                fB[ms] = *(const half8*)(pB + sg);
            }
            __syncthreads();  // all reads done; LDS free for next stage
            if (ss < 7) stage(col, ss + 1);
            else if (col < 7) stage(col + 1, 0);
#pragma unroll
            for (int ms = 0; ms < 4; ++ms) {
                acc0 = __builtin_amdgcn_mfma_f32_32x32x16_f16(fA0[ms], fB[ms], acc0, 0, 0, 0);
                acc1 = __builtin_amdgcn_mfma_f32_32x32x16_f16(fA1[ms], fB[ms], acc1, 0, 0, 0);
            }
        }

        // epilogue: s = cnormP[code] + acc (all positive); fold running min; margin-append
        const int codeb = kbase + (col << 7) + wp * 64;
        float sc[32];
        float lmin = 3.4e38f;
#pragma unroll
        for (int pi = 0; pi < 2; ++pi)
#pragma unroll
            for (int g = 0; g < 4; ++g) {
                float4 cn = *(const float4*)(cnormP + codeb + pi * 32 + g * 8 + hf * 4);
                const floatx16& A = pi ? acc1 : acc0;
                float s0 = cn.x + A[g * 4 + 0];
                float s1 = cn.y + A[g * 4 + 1];
                float s2 = cn.z + A[g * 4 + 2];
                float s3 = cn.w + A[g * 4 + 3];
                sc[pi * 16 + g * 4 + 0] = s0;
                sc[pi * 16 + g * 4 + 1] = s1;
                sc[pi * 16 + g * 4 + 2] = s2;
                sc[pi * 16 + g * 4 + 3] = s3;
                lmin = fminf(lmin, fminf(fminf(s0, s1), fminf(s2, s3)));
            }
        const int tloc = wq * 32 + l31;
        atomicMin(&Rmin[tloc], __float_as_uint(lmin));
        __syncthreads();
        const float thr = __uint_as_float(Rmin[tloc]) + MARGIN;
        const uint32_t tokg = (uint32_t)(n0 + tloc);
#pragma unroll
        for (int pi = 0; pi < 2; ++pi)
#pragma unroll
            for (int g = 0; g < 4; ++g)
#pragma unroll
                for (int q = 0; q < 4; ++q) {
                    if (sc[pi * 16 + g * 4 + q] <= thr) {
                        uint32_t idx = atomicAdd(counter, 1u);
                        uint32_t code = (uint32_t)(codeb + pi * 32 + g * 8 + hf * 4 + q);
                        if (idx < CAP) list[idx] = (tokg << 13) | code;
                    }
                }
    }
}

// ---- pass 2: exact fp32 rescore of candidates ----
__global__ void rescore_kernel(const float* __restrict__ z, const float* __restrict__ cb,
                               const float* __restrict__ cnormP,
                               const uint32_t* __restrict__ list,
                               const uint32_t* __restrict__ counter,
                               unsigned long long* __restrict__ wexact) {
    uint32_t cnt = *counter;
    if (cnt > CAP) cnt = CAP;
    const int l = threadIdx.x & 63;
    const int stride = gridDim.x * 4;
    for (uint32_t i = blockIdx.x * 4 + (threadIdx.x >> 6); i < cnt; i += stride) {
        uint32_t e = list[i];
        int tok = e >> 13, code = e & 8191;
        int b = tok >> 8, t = tok & 255;
        const float* zp = z + ((size_t)b * EMBED_DIM) * T_ + t;
        const float* cp = cb + (size_t)code * EMBED_DIM;
        float dot = 0.f;
#pragma unroll
        for (int j = 0; j < 8; ++j) {
            int d = l + (j << 6);
            dot += zp[(size_t)d * T_] * cp[d];
        }
#pragma unroll
        for (int m = 32; m; m >>= 1) dot += __shfl_xor(dot, m, 64);
        if (l == 0) {
            float s = cnormP[code] - 2.0f * dot;
            unsigned long long key = ((unsigned long long)__float_as_uint(s) << 32) | (uint32_t)code;
            atomicMin(&wexact[tok], key);
        }
    }
}

__global__ void gather_kernel(const float* __restrict__ z, const float* __restrict__ cb,
                              const unsigned long long* __restrict__ wexact,
                              float* __restrict__ out, int* __restrict__ counts,
                              float* __restrict__ sse_acc) {
    __shared__ unsigned int sIdx[64];
    __shared__ float red[4];
    const int tid = threadIdx.x;
    const int n0 = blockIdx.x * 64;
    const int b = n0 >> 8;
    const int t0 = n0 & 255;
    if (tid < 64) {
        unsigned int idx = (unsigned int)(wexact[n0 + tid] & 0xffffffffULL);
        sIdx[tid] = idx;
        atomicAdd(&counts[idx], 1);
    }
    __syncthreads();
    const int w = tid >> 6;
    const int lane = tid & 63;
    const float* crow = cb + (size_t)sIdx[lane] * EMBED_DIM;
    const size_t base = ((size_t)b * EMBED_DIM) * T_ + (size_t)(t0 + lane);
    float sse = 0.f;
    for (int d = w; d < EMBED_DIM; d += 4) {
        float v = crow[d];
        size_t o = base + (size_t)d * T_;
        float diff = v - z[o];
        out[o] = v;  // z + sg(z_q - z) == z_q numerically
        sse += diff * diff;
    }
    for (int m = 32; m; m >>= 1) sse += __shfl_xor(sse, m, 64);
    if (lane == 0) red[w] = sse;
    __syncthreads();
    if (tid == 0) atomicAdd(sse_acc, red[0] + red[1] + red[2] + red[3]);
}

__global__ void finalize_kernel(const int* __restrict__ counts,
                                const float* __restrict__ sse_acc,
                                float* __restrict__ out) {
    __shared__ float red[4];
    const int tid = threadIdx.x;
    float e = 0.f;
    for (int k = tid; k < NUM_EMBEDS; k += 256) {
        float p = (float)counts[k] * (1.0f / (float)N_TOK);
        e += p * logf(p + 1e-10f);
    }
    for (int m = 32; m; m >>= 1) e += __shfl_xor(e, m, 64);
    if ((tid & 63) == 0) red[tid >> 6] = e;
    __syncthreads();
    if (tid == 0) {
        float ent = red[0] + red[1] + red[2] + red[3];
        size_t off = (size_t)B_ * EMBED_DIM * T_;
        out[off + 0] = (ALPHA_ * BETA_) * sse_acc[0] / (float)((size_t)N_TOK * EMBED_DIM);
        out[off + 1] = expf(-ent);
    }
}

extern "C" void kernel_launch(void* const* d_in, const int* in_sizes, int n_in,
                              void* d_out, int out_size, void* d_ws, size_t ws_size,
                              hipStream_t stream) {
    const float* z = (const float*)d_in[0];
    const float* cb = (const float*)d_in[1];
    float* out = (float*)d_out;
    char* ws = (char*)d_ws;
    unsigned long long* wexact = (unsigned long long*)ws;
    float* cnormP = (float*)(ws + 65536);
    int* counts = (int*)(ws + 98304);
    float* sse = (float*)(ws + 131072);
    uint32_t* counter = (uint32_t*)(ws + 131076);
    _Float16* cb_h = (_Float16*)(ws + (1ull << 20));
    _Float16* zt_h = (_Float16*)(ws + (9ull << 20));
    uint32_t* list = (uint32_t*)(ws + (17ull << 20));

    hipMemsetAsync(wexact, 0xFF, NUM_EMBEDS * sizeof(unsigned long long), stream);
    hipMemsetAsync(counts, 0, NUM_EMBEDS * sizeof(int) + 8, stream);  // counts + sse + counter

    pack_cb_kernel<<<NUM_EMBEDS / 4, 256, 0, stream>>>(cb, cb_h, cnormP);
    pack_z_kernel<<<N_TOK / 64, 256, 0, stream>>>(z, zt_h);
    argmin_kernel<<<dim3(N_TOK / TOKB, NUM_EMBEDS / KCH), 256, 0, stream>>>(cb_h, zt_h, cnormP, list, counter);
    rescore_kernel<<<256, 256, 0, stream>>>(z, cb, cnormP, list, counter, wexact);
    gather_kernel<<<N_TOK / 64, 256, 0, stream>>>(z, cb, wexact, out, counts, sse);
    finalize_kernel<<<1, 256, 0, stream>>>(counts, sse, out);
}

// Round 6
// 363.342 us; speedup vs baseline: 7.5061x; 7.5061x over previous
//
#include <hip/hip_runtime.h>
#include <stdint.h>

typedef _Float16 half8 __attribute__((ext_vector_type(8)));
typedef float floatx16 __attribute__((ext_vector_type(16)));
typedef unsigned long long u64;

#define ALPHA_ 1.0f
#define BETA_ 0.25f
#define NUM_EMBEDS 8192
#define EMBED_DIM 512
#define B_ 32
#define T_ 256
#define N_TOK 8192
#define THR_GAP 2e-3f

// ---------------- ws layout (bytes) ----------------
// wexact   @ 0        (64 KB)  u64 packed exact min: monokey<<32 | code
// cnorm    @ 65536    (32 KB)  ||c||^2
// counts   @ 98304    (32 KB)
// sse      @ 131072   (4 B)
// nflag    @ 131076   (4 B)
// worklist @ 131080   (32 KB)
// slot_m1  @ 1  MB    (4 MB)   u64 [64 chunks][8192 tok] block min1 key
// slot_d   @ 5  MB    (1 MB)   f16 [64][8192] (min2 - min1) delta
// cb_i     @ 6  MB    (16 MB)  f16 h/m interleaved codebook [k][d]
// zt_i     @ 22 MB    (16 MB)  f16 h/m interleaved -2*z^T [n][d]
// ---------------------------------------------------
// interleaved row layout: row*1024 + grp*16 + plane*8  (grp = d/8, plane 0=h 1=m*2048)

typedef __attribute__((address_space(1))) const void ga_void;
typedef __attribute__((address_space(3))) void ls_void;
__device__ __forceinline__ void gl_lds16(const void* g, void* l) {
    __builtin_amdgcn_global_load_lds((ga_void*)g, (ls_void*)l, 16, 0, 0);
}

__device__ __forceinline__ uint32_t mono(float s) {
    uint32_t u = __float_as_uint(s);
    return (u & 0x80000000u) ? ~u : (u | 0x80000000u);
}
__device__ __forceinline__ float unmono(uint32_t v) {
    return __uint_as_float((v & 0x80000000u) ? (v ^ 0x80000000u) : ~v);
}

__global__ void pack_cb_kernel(const float* __restrict__ cb, _Float16* __restrict__ ci,
                               float* __restrict__ cnorm) {
    int row = blockIdx.x * 4 + (threadIdx.x >> 6);
    int lane = threadIdx.x & 63;
    const float* src = cb + (size_t)row * EMBED_DIM + lane * 8;
    float4 v0 = *(const float4*)src;
    float4 v1 = *(const float4*)(src + 4);
    float x[8] = {v0.x, v0.y, v0.z, v0.w, v1.x, v1.y, v1.z, v1.w};
    half8 hh, mm;
    float s = 0.f;
#pragma unroll
    for (int j = 0; j < 8; ++j) {
        s += x[j] * x[j];
        _Float16 hv = (_Float16)x[j];
        hh[j] = hv;
        mm[j] = (_Float16)((x[j] - (float)hv) * 2048.0f);
    }
    _Float16* dst = ci + (size_t)row * 1024 + lane * 16;
    *(half8*)dst = hh;
    *(half8*)(dst + 8) = mm;
#pragma unroll
    for (int d = 32; d; d >>= 1) s += __shfl_xor(s, d, 64);
    if (lane == 0) cnorm[row] = s;
}

__global__ void pack_z_kernel(const float* __restrict__ z, _Float16* __restrict__ zi) {
    int tid = threadIdx.x;
    int lane = tid & 63, ds = tid >> 6;
    int b = blockIdx.x >> 2;
    int t = ((blockIdx.x & 3) << 6) + lane;
    size_t n = (size_t)b * T_ + t;
    for (int g = 0; g < 16; ++g) {
        int d0 = g * 32 + ds * 8;
        const float* src = z + ((size_t)b * EMBED_DIM + d0) * T_ + t;
        half8 hh, mm;
#pragma unroll
        for (int j = 0; j < 8; ++j) {
            float x = -2.0f * src[(size_t)j * T_];
            _Float16 hv = (_Float16)x;
            hh[j] = hv;
            mm[j] = (_Float16)((x - (float)hv) * 2048.0f);
        }
        _Float16* dst = zi + n * 1024 + (size_t)(g * 4 + ds) * 16;
        *(half8*)dst = hh;
        *(half8*)(dst + 8) = mm;
    }
}

// ---- pass 1: 2-plane argmin GEMM, 128 codes x 128 tokens, BK=32, dbuf, 1 barrier/step ----
#define MFMA16(a, b, c) __builtin_amdgcn_mfma_f32_32x32x16_f16(a, b, c, 0, 0, 0)

__global__ __launch_bounds__(256, 2) void argmin_kernel(
    const _Float16* __restrict__ cb_i, const _Float16* __restrict__ zt_i,
    const float* __restrict__ cnorm, u64* __restrict__ slot_m1,
    _Float16* __restrict__ slot_d) {
    __shared__ _Float16 As[2][8192];  // [buf][128 rows x 64 halves (32 elems, h/m 16B interleave)]
    __shared__ _Float16 Bs[2][8192];
    __shared__ u64 sK[128];     // cross-wave (wp) merge buffers
    __shared__ float sV1[128], sV2[128];
    const int tid = threadIdx.x;
    const int l = tid & 63;
    const int wv = tid >> 6;
    const int l31 = l & 31;
    const int hf = l >> 5;
    const int wp = wv >> 1, wq = wv & 1;
    const int n0 = blockIdx.x * 128;
    const int c0 = blockIdx.y * 128;

    // staging: waves 0,1 -> A rows 0..63 / 64..127 ; waves 2,3 -> B rows
    const bool isA = wv < 2;
    const _Float16* gsrc = isA ? cb_i : zt_i;
    const int rbase = (isA ? c0 : n0) + ((wv & 1) << 6);
    const int srow = l >> 3;             // 0..7 row-within-8
    const int sseg = (l & 7) ^ srow;     // XOR swizzle (phys slot l&7 <- global seg sseg)
    const size_t lanefix = (size_t)(rbase + srow) * 1024 + sseg * 8;

    floatx16 acc1[2][2], acc2[2][2];
#pragma unroll
    for (int a = 0; a < 2; ++a)
#pragma unroll
        for (int b = 0; b < 2; ++b)
#pragma unroll
            for (int r = 0; r < 16; ++r) { acc1[a][b][r] = 0.f; acc2[a][b][r] = 0.f; }

    auto stage = [&](int p, int s) {
        const _Float16* gs = gsrc + lanefix + (size_t)s * 64;
        _Float16* lb = (isA ? As[p] : Bs[p]) + ((wv & 1) << 12);
#pragma unroll
        for (int j = 0; j < 8; ++j)
            gl_lds16(gs + (size_t)j * 8192, lb + j * 512);
    };

    stage(0, 0);
    __syncthreads();
    for (int s = 0; s < 16; ++s) {
        const int p = s & 1;
        if (s < 15) stage(p ^ 1, s + 1);
        const _Float16* Ab = As[p] + (wp * 64 + l31) * 64;
        const _Float16* Bb = Bs[p] + (wq * 64 + l31) * 64;
        const int rs = l31 & 7;
#pragma unroll
        for (int kk = 0; kk < 2; ++kk) {
            const int j = kk * 2 + hf;
            const int ph = ((2 * j) ^ rs) * 8;
            const int pm = ((2 * j + 1) ^ rs) * 8;
            half8 Ah0 = *(const half8*)(Ab + ph), Am0 = *(const half8*)(Ab + pm);
            half8 Ah1 = *(const half8*)(Ab + 2048 + ph), Am1 = *(const half8*)(Ab + 2048 + pm);
            half8 Bh0 = *(const half8*)(Bb + ph), Bm0 = *(const half8*)(Bb + pm);
            half8 Bh1 = *(const half8*)(Bb + 2048 + ph), Bm1 = *(const half8*)(Bb + 2048 + pm);
            acc1[0][0] = MFMA16(Ah0, Bh0, acc1[0][0]);
            acc2[0][0] = MFMA16(Ah0, Bm0, acc2[0][0]);
            acc2[0][0] = MFMA16(Am0, Bh0, acc2[0][0]);
            acc1[0][1] = MFMA16(Ah0, Bh1, acc1[0][1]);
            acc2[0][1] = MFMA16(Ah0, Bm1, acc2[0][1]);
            acc2[0][1] = MFMA16(Am0, Bh1, acc2[0][1]);
            acc1[1][0] = MFMA16(Ah1, Bh0, acc1[1][0]);
            acc2[1][0] = MFMA16(Ah1, Bm0, acc2[1][0]);
            acc2[1][0] = MFMA16(Am1, Bh0, acc2[1][0]);
            acc1[1][1] = MFMA16(Ah1, Bh1, acc1[1][1]);
            acc2[1][1] = MFMA16(Ah1, Bm1, acc2[1][1]);
            acc2[1][1] = MFMA16(Am1, Bh1, acc2[1][1]);
        }
        __syncthreads();
    }

    // epilogue: per (lane,qi) -> one token, this wave covers 32 codes (wp-half)
    u64 km[2]; float kv1[2], kv2[2];
#pragma unroll
    for (int qi = 0; qi < 2; ++qi) {
        u64 m1k = ~0ULL;
        float m1v = 3.4e38f, m2 = 3.4e38f;
#pragma unroll
        for (int ti = 0; ti < 2; ++ti)
#pragma unroll
            for (int g = 0; g < 4; ++g) {
                const int cb4 = c0 + wp * 64 + ti * 32 + g * 8 + hf * 4;
                float4 cn = *(const float4*)(cnorm + cb4);
                const floatx16& A1 = acc1[ti][qi];
                const floatx16& A2 = acc2[ti][qi];
                float sv[4] = {cn.x + A1[g * 4 + 0] + A2[g * 4 + 0] * (1.0f / 2048.0f),
                               cn.y + A1[g * 4 + 1] + A2[g * 4 + 1] * (1.0f / 2048.0f),
                               cn.z + A1[g * 4 + 2] + A2[g * 4 + 2] * (1.0f / 2048.0f),
                               cn.w + A1[g * 4 + 3] + A2[g * 4 + 3] * (1.0f / 2048.0f)};
#pragma unroll
                for (int q = 0; q < 4; ++q) {
                    u64 key = ((u64)mono(sv[q]) << 32) | (uint32_t)(cb4 + q);
                    if (key < m1k) { m2 = m1v; m1v = sv[q]; m1k = key; }
                    else m2 = fminf(m2, sv[q]);
                }
            }
        // merge across the hf pair (same token, other half of code m%8)
        u64 ok = __shfl_xor(m1k, 32, 64);
        float ov = __shfl_xor(m1v, 32, 64);
        float om2 = __shfl_xor(m2, 32, 64);
        if (ok < m1k) { m2 = fminf(fminf(m2, om2), m1v); m1v = ov; m1k = ok; }
        else m2 = fminf(fminf(m2, om2), ov);
        km[qi] = m1k; kv1[qi] = m1v; kv2[qi] = m2;
    }
    // cross-wave merge: wp=1 publishes, wp=0 merges + stores (fixes R5 store race)
    if (wp == 1 && hf == 0) {
#pragma unroll
        for (int qi = 0; qi < 2; ++qi) {
            int idx = wq * 64 + qi * 32 + l31;
            sK[idx] = km[qi]; sV1[idx] = kv1[qi]; sV2[idx] = kv2[qi];
        }
    }
    __syncthreads();
    if (wp == 0 && hf == 0) {
#pragma unroll
        for (int qi = 0; qi < 2; ++qi) {
            int idx = wq * 64 + qi * 32 + l31;
            u64 m1k = km[qi]; float m1v = kv1[qi], m2 = kv2[qi];
            u64 ok = sK[idx]; float ov = sV1[idx], om2 = sV2[idx];
            if (ok < m1k) { m2 = fminf(fminf(m2, om2), m1v); m1v = ov; m1k = ok; }
            else m2 = fminf(fminf(m2, om2), ov);
            int tok = n0 + idx;
            slot_m1[((size_t)blockIdx.y << 13) + tok] = m1k;
            slot_d[((size_t)blockIdx.y << 13) + tok] = (_Float16)(m2 - m1v);
        }
    }
}

// ---- combine: merge 64 chunk summaries per token; gap-test; worklist the unsafe ----
__global__ void combine_kernel(const u64* __restrict__ slot_m1, const _Float16* __restrict__ slot_d,
                               u64* __restrict__ wexact, int* __restrict__ worklist,
                               int* __restrict__ nflag) {
    int tok = blockIdx.x * 256 + threadIdx.x;
    u64 g1 = ~0ULL;
    float g1v = 3.4e38f, g2 = 3.4e38f;
    for (int c = 0; c < 64; ++c) {
        u64 k = slot_m1[((size_t)c << 13) + tok];
        float kv = unmono((uint32_t)(k >> 32));
        float v2 = kv + (float)slot_d[((size_t)c << 13) + tok];
        if (k < g1) { g2 = fminf(g2, g1v); g1 = k; g1v = kv; }
        else g2 = fminf(g2, kv);
        g2 = fminf(g2, v2);
    }
    if (g2 - g1v > THR_GAP) wexact[tok] = g1;
    else { int i = atomicAdd(nflag, 1); if (i < 8192) worklist[i] = tok; }
}

// ---- fallback: exact fp32 rescore of flagged tokens over all codes ----
__global__ void fallback_kernel(const float* __restrict__ z, const float* __restrict__ cb,
                                const float* __restrict__ cnorm,
                                const int* __restrict__ worklist, const int* __restrict__ nflag,
                                u64* __restrict__ wexact) {
    int n = *nflag;
    if (n > 8192) n = 8192;
    const int l = threadIdx.x & 63, wv = threadIdx.x >> 6;
    const int cbase = blockIdx.x * 128;
    for (int fi = blockIdx.y; fi < n; fi += gridDim.y) {
        int tok = worklist[fi];
        int b = tok >> 8, t = tok & 255;
        const float* zp = z + ((size_t)b * EMBED_DIM) * T_ + t;
        float zr[8];
#pragma unroll
        for (int j = 0; j < 8; ++j) zr[j] = zp[(size_t)(l * 8 + j) * T_];
        u64 m1 = ~0ULL;
        for (int j = 0; j < 32; ++j) {
            int c = cbase + wv + j * 4;
            const float* cp = cb + (size_t)c * EMBED_DIM + l * 8;
            float4 a = *(const float4*)cp, bb = *(const float4*)(cp + 4);
            float dot = zr[0] * a.x + zr[1] * a.y + zr[2] * a.z + zr[3] * a.w +
                        zr[4] * bb.x + zr[5] * bb.y + zr[6] * bb.z + zr[7] * bb.w;
#pragma unroll
            for (int m = 32; m; m >>= 1) dot += __shfl_xor(dot, m, 64);
            if (l == 0) {
                float s = cnorm[c] - 2.0f * dot;
                u64 key = ((u64)mono(s) << 32) | (uint32_t)c;
                if (key < m1) m1 = key;
            }
        }
        if (l == 0) atomicMin(&wexact[tok], m1);
    }
}

__global__ void gather_kernel(const float* __restrict__ z, const float* __restrict__ cb,
                              const u64* __restrict__ wexact,
                              float* __restrict__ out, int* __restrict__ counts,
                              float* __restrict__ sse_acc) {
    __shared__ unsigned int sIdx[64];
    __shared__ float red[4];
    const int tid = threadIdx.x;
    const int n0 = blockIdx.x * 64;
    const int b = n0 >> 8;
    const int t0 = n0 & 255;
    if (tid < 64) {
        unsigned int idx = (unsigned int)(wexact[n0 + tid] & 0xffffffffULL);
        sIdx[tid] = idx;
        atomicAdd(&counts[idx], 1);
    }
    __syncthreads();
    const int w = tid >> 6;
    const int lane = tid & 63;
    const float* crow = cb + (size_t)sIdx[lane] * EMBED_DIM;
    const size_t base = ((size_t)b * EMBED_DIM) * T_ + (size_t)(t0 + lane);
    float sse = 0.f;
    for (int d = w; d < EMBED_DIM; d += 4) {
        float v = crow[d];
        size_t o = base + (size_t)d * T_;
        float diff = v - z[o];
        out[o] = v;
        sse += diff * diff;
    }
    for (int m = 32; m; m >>= 1) sse += __shfl_xor(sse, m, 64);
    if (lane == 0) red[w] = sse;
    __syncthreads();
    if (tid == 0) atomicAdd(sse_acc, red[0] + red[1] + red[2] + red[3]);
}

__global__ void finalize_kernel(const int* __restrict__ counts,
                                const float* __restrict__ sse_acc,
                                float* __restrict__ out) {
    __shared__ float red[4];
    const int tid = threadIdx.x;
    float e = 0.f;
    for (int k = tid; k < NUM_EMBEDS; k += 256) {
        float p = (float)counts[k] * (1.0f / (float)N_TOK);
        e += p * logf(p + 1e-10f);
    }
    for (int m = 32; m; m >>= 1) e += __shfl_xor(e, m, 64);
    if ((tid & 63) == 0) red[tid >> 6] = e;
    __syncthreads();
    if (tid == 0) {
        float ent = red[0] + red[1] + red[2] + red[3];
        size_t off = (size_t)B_ * EMBED_DIM * T_;
        out[off + 0] = (ALPHA_ * BETA_) * sse_acc[0] / (float)((size_t)N_TOK * EMBED_DIM);
        out[off + 1] = expf(-ent);
    }
}

extern "C" void kernel_launch(void* const* d_in, const int* in_sizes, int n_in,
                              void* d_out, int out_size, void* d_ws, size_t ws_size,
                              hipStream_t stream) {
    const float* z = (const float*)d_in[0];
    const float* cb = (const float*)d_in[1];
    float* out = (float*)d_out;
    char* ws = (char*)d_ws;
    u64* wexact = (u64*)ws;
    float* cnorm = (float*)(ws + 65536);
    int* counts = (int*)(ws + 98304);
    float* sse = (float*)(ws + 131072);
    int* nflag = (int*)(ws + 131076);
    int* worklist = (int*)(ws + 131080);
    u64* slot_m1 = (u64*)(ws + (1ull << 20));
    _Float16* slot_d = (_Float16*)(ws + (5ull << 20));
    _Float16* cb_i = (_Float16*)(ws + (6ull << 20));
    _Float16* zt_i = (_Float16*)(ws + (22ull << 20));

    hipMemsetAsync(wexact, 0xFF, NUM_EMBEDS * sizeof(u64), stream);
    hipMemsetAsync(counts, 0, NUM_EMBEDS * sizeof(int) + 8, stream);  // counts + sse + nflag

    pack_cb_kernel<<<NUM_EMBEDS / 4, 256, 0, stream>>>(cb, cb_i, cnorm);
    pack_z_kernel<<<N_TOK / 64, 256, 0, stream>>>(z, zt_i);
    argmin_kernel<<<dim3(N_TOK / 128, NUM_EMBEDS / 128), 256, 0, stream>>>(cb_i, zt_i, cnorm, slot_m1, slot_d);
    combine_kernel<<<N_TOK / 256, 256, 0, stream>>>(slot_m1, slot_d, wexact, worklist, nflag);
    fallback_kernel<<<dim3(64, 16), 256, 0, stream>>>(z, cb, cnorm, worklist, nflag, wexact);
    gather_kernel<<<N_TOK / 64, 256, 0, stream>>>(z, cb, wexact, out, counts, sse);
    finalize_kernel<<<1, 256, 0, stream>>>(counts, sse, out);
}